// Round 5
// baseline (237.624 us; speedup 1.0000x reference)
//
#include <hip/hip_runtime.h>
#include <math.h>

#define RAD2DEG 57.29577951308232f

constexpr int S1_BLOCKS = 2048;
constexpr int S1_TPB    = 256;

// Absolute angular distance in degrees between vectors (ax,ay) and (bx,by).
// == wrap(atan2(ay,ax)*RAD2DEG - atan2(by,bx)*RAD2DEG) from the reference.
__device__ __forceinline__ float angdist_deg(float ax, float ay,
                                             float bx, float by) {
    float dot = ax * bx + ay * by;
    float cr  = fabsf(ay * bx - ax * by);
    float ad  = fabsf(dot);
    float mn  = fminf(cr, ad);
    float mx  = fmaxf(cr, ad);
    float t   = mn * __builtin_amdgcn_rcpf(fmaxf(mx, 1e-37f));
    float s   = t * t;
    // minimax poly for atan(t), t in [0,1]; max err ~2.3e-5 rad (~0.0013 deg)
    float p = fmaf(s, -0.01172120f, 0.05265332f);
    p = fmaf(s, p, -0.11643287f);
    p = fmaf(s, p,  0.19354346f);
    p = fmaf(s, p, -0.33262347f);
    p = fmaf(s, p,  0.99997726f);
    float a = t * p;                                   // [0, pi/4]
    a = (cr > ad)    ? (1.57079632679489662f - a) : a; // [0, pi/2]
    a = (dot < 0.0f) ? (3.14159265358979323f - a) : a; // [0, pi]
    return a * RAD2DEG;
}

__device__ __forceinline__ void per_row(
    float l1x, float l2x, float l1y, float l2y, float l1z, float l2z,
    float e1x, float e1y, float e1z, float e2x, float e2y, float e2z,
    int mw,
    float& sS, float& sM, float& sC0, float& sM1, float& sM2)
{
    float dx, dy, dz;
    dx = e1x - l1x; dy = e1y - l1y; dz = e1z - l1z;
    float d11 = dx*dx + dy*dy + dz*dz;
    dx = e2x - l2x; dy = e2y - l2y; dz = e2z - l2z;
    float d22 = dx*dx + dy*dy + dz*dz;
    dx = e2x - l1x; dy = e2y - l1y; dz = e2z - l1z;
    float d21 = dx*dx + dy*dy + dz*dz;
    dx = e1x - l2x; dy = e1y - l2y; dz = e1z - l2z;
    float d12 = dx*dx + dy*dy + dz*dz;

    sS += d11;

    float mixed = fminf(d11 + d22, d21 + d12) * (1.0f / 3.0f);
    float m = (mw != 0) ? 1.0f : 0.0f;
    sM  += m * mixed;
    sC0 += 1.0f - m;

    float e11 = angdist_deg(l1x, l1y, e1x, e1y);
    float e22 = angdist_deg(l2x, l2y, e2x, e2y);
    float e12 = angdist_deg(l1x, l1y, e2x, e2y);
    float e21 = angdist_deg(l2x, l2y, e1x, e1y);

    bool ud = (e11 + e22) < (e12 + e21);
    sM1 += ud ? e11 : e12;
    sM2 += ud ? e22 : e21;
}

struct PairData {
    float4 L0, L1, L2, E0, E1, E2;
    int2   mw;
};

__device__ __forceinline__ PairData load_pair(
    const float4* __restrict__ lab4, const float4* __restrict__ est4,
    const int2* __restrict__ mix2, long long p)
{
    PairData d;
    const float4* lv = lab4 + p * 3;
    const float4* ev = est4 + p * 3;
    d.L0 = lv[0]; d.L1 = lv[1]; d.L2 = lv[2];
    d.E0 = ev[0]; d.E1 = ev[1]; d.E2 = ev[2];
    d.mw = mix2[p];
    return d;
}

__device__ __forceinline__ void compute_pair(
    const PairData& d,
    float& sS, float& sM, float& sC0, float& sM1, float& sM2)
{
    per_row(d.L0.x, d.L0.y, d.L0.z, d.L0.w, d.L1.x, d.L1.y,
            d.E0.x, d.E0.y, d.E0.z, d.E0.w, d.E1.x, d.E1.y,
            d.mw.x, sS, sM, sC0, sM1, sM2);
    per_row(d.L1.z, d.L1.w, d.L2.x, d.L2.y, d.L2.z, d.L2.w,
            d.E1.z, d.E1.w, d.E2.x, d.E2.y, d.E2.z, d.E2.w,
            d.mw.y, sS, sM, sC0, sM1, sM2);
}

// __launch_bounds__(256, 4): allow up to ~128 VGPRs so the software-pipeline
// prefetch (26 dwords/pair) stays resident instead of being register-throttled
// (round 4 compiled to 36 VGPRs and serialized the loads).
__global__ __launch_bounds__(S1_TPB, 4) void stage1_kernel(
    const float* __restrict__ label,
    const float* __restrict__ est,
    const int*   __restrict__ mix,
    float* __restrict__ partials,   // [gridDim.x][5]
    long long P)                    // number of row-pairs = B/2
{
    const int tid = threadIdx.x;

    // XCD-aware swizzle: blocks are dispatched round-robin over 8 XCDs.
    // Remap so each XCD processes one contiguous slab of the input
    // (DRAM page / channel locality). Performance heuristic only.
    const int nb   = gridDim.x;
    const int xcd  = blockIdx.x & 7;
    const int slot = blockIdx.x >> 3;
    const int b    = xcd * (nb >> 3) + slot;

    const long long ppb   = (P + nb - 1) / nb;
    const long long start = (long long)b * ppb;
    const long long end   = (start + ppb < P) ? (start + ppb) : P;

    const float4* lab4 = (const float4*)label;
    const float4* est4 = (const float4*)est;
    const int2*   mix2 = (const int2*)mix;

    float sS = 0.f, sM = 0.f, sC0 = 0.f, sM1 = 0.f, sM2 = 0.f;

    // Software pipeline: prefetch pair p+T while computing pair p, so each
    // wave keeps ~6.6 KB of loads in flight *during* compute (100% duty
    // cycle) instead of load->drain->compute.
    long long p = start + tid;
    if (p < end) {
        PairData cur = load_pair(lab4, est4, mix2, p);
        for (; p + S1_TPB < end; p += S1_TPB) {
            PairData nxt = load_pair(lab4, est4, mix2, p + S1_TPB);
            compute_pair(cur, sS, sM, sC0, sM1, sM2);
            cur = nxt;
        }
        compute_pair(cur, sS, sM, sC0, sM1, sM2);
    }

    // wave (64-lane) shuffle reduction
    for (int off = 32; off > 0; off >>= 1) {
        sS  += __shfl_down(sS,  off, 64);
        sM  += __shfl_down(sM,  off, 64);
        sC0 += __shfl_down(sC0, off, 64);
        sM1 += __shfl_down(sM1, off, 64);
        sM2 += __shfl_down(sM2, off, 64);
    }

    __shared__ float red[S1_TPB / 64][5];
    const int wid = tid >> 6, lane = tid & 63;
    if (lane == 0) {
        red[wid][0] = sS; red[wid][1] = sM; red[wid][2] = sC0;
        red[wid][3] = sM1; red[wid][4] = sM2;
    }
    __syncthreads();
    if (tid == 0) {
        float r0 = 0.f, r1 = 0.f, r2 = 0.f, r3 = 0.f, r4 = 0.f;
        #pragma unroll
        for (int w = 0; w < S1_TPB / 64; ++w) {
            r0 += red[w][0]; r1 += red[w][1]; r2 += red[w][2];
            r3 += red[w][3]; r4 += red[w][4];
        }
        float* out = partials + (size_t)b * 5;
        out[0] = r0; out[1] = r1; out[2] = r2; out[3] = r3; out[4] = r4;
    }
}

__global__ __launch_bounds__(256) void stage2_kernel(
    const float* __restrict__ partials,
    float* __restrict__ out,
    int nblocks,
    long long Btot)
{
    const int tid = threadIdx.x;
    double aS = 0, aM = 0, aC0 = 0, aM1 = 0, aM2 = 0;
    for (int r = tid; r < nblocks; r += 256) {
        const float* row = partials + (size_t)r * 5;
        aS += row[0]; aM += row[1]; aC0 += row[2]; aM1 += row[3]; aM2 += row[4];
    }
    for (int off = 32; off > 0; off >>= 1) {
        aS  += __shfl_down(aS,  off, 64);
        aM  += __shfl_down(aM,  off, 64);
        aC0 += __shfl_down(aC0, off, 64);
        aM1 += __shfl_down(aM1, off, 64);
        aM2 += __shfl_down(aM2, off, 64);
    }
    __shared__ double red[4][5];
    const int wid = tid >> 6, lane = tid & 63;
    if (lane == 0) {
        red[wid][0] = aS; red[wid][1] = aM; red[wid][2] = aC0;
        red[wid][3] = aM1; red[wid][4] = aM2;
    }
    __syncthreads();
    if (tid == 0) {
        double S = 0, M = 0, C0 = 0, M1 = 0, M2 = 0;
        #pragma unroll
        for (int w = 0; w < 4; ++w) {
            S += red[w][0]; M += red[w][1]; C0 += red[w][2];
            M1 += red[w][3]; M2 += red[w][4];
        }
        const double Bd = (double)Btot;
        const double single_loss = S / (3.0 * Bd);
        out[0] = (float)((C0 * single_loss + M) / Bd);
        out[1] = (float)(M1 / Bd);
        out[2] = (float)(M2 / Bd);
    }
}

extern "C" void kernel_launch(void* const* d_in, const int* in_sizes, int n_in,
                              void* d_out, int out_size, void* d_ws, size_t ws_size,
                              hipStream_t stream) {
    const float* label = (const float*)d_in[0];   // (B,3,2) f32
    const float* est   = (const float*)d_in[1];   // (B,6)   f32
    const int*   mix   = (const int*)d_in[2];     // (B,)    i32
    float* out = (float*)d_out;
    float* partials = (float*)d_ws;

    const long long B = (long long)in_sizes[2];
    const long long P = B / 2;  // B = 4194304, even

    stage1_kernel<<<S1_BLOCKS, S1_TPB, 0, stream>>>(label, est, mix, partials, P);
    stage2_kernel<<<1, 256, 0, stream>>>(partials, out, S1_BLOCKS, B);
}